// Round 1
// baseline (446.117 us; speedup 1.0000x reference)
//
#include <hip/hip_runtime.h>
#include <math.h>

// Problem constants (fixed by setup_inputs)
#define BATCH 8
#define QLEN 900
#define EMBED 256
#define HEADS 8
#define LEVELS 4
#define POINTS 4
#define HEAD_DIM 32
#define NUM_KEYS 13294
#define BQ (BATCH * QLEN)          // 7200
#define MROWS_V (BATCH * NUM_KEYS) // 106352

__constant__ const int c_LH[4] = {100, 50, 25, 13};
__constant__ const int c_LW[4] = {100, 50, 25, 13};
__constant__ const int c_LS[4] = {0, 10000, 12500, 13125};

// ---------------------------------------------------------------------------
// fp32 GEMM: C[M,N] = A[M,K] @ W[K,N] + bias[N]
// 64x64 tile, BK=16, 256 threads, 4x4 per-thread register block.
// Requires: K % 16 == 0, N % 64 == 0. M guarded.
// ---------------------------------------------------------------------------
#define BM 64
#define BN 64
#define BK 16

__global__ __launch_bounds__(256)
void gemm_bias_kernel(const float* __restrict__ A, const float* __restrict__ W,
                      const float* __restrict__ bias, float* __restrict__ C,
                      int M, int N, int K) {
    __shared__ float As[BK][BM + 4];   // transposed A tile, padded
    __shared__ float Bs[BK][BN + 4];

    const int tid = threadIdx.x;
    const int tx = tid & 15;
    const int ty = tid >> 4;
    const int m0 = blockIdx.x * BM;
    const int n0 = blockIdx.y * BN;

    float acc[4][4];
#pragma unroll
    for (int i = 0; i < 4; ++i)
#pragma unroll
        for (int j = 0; j < 4; ++j) acc[i][j] = 0.f;

    const int ar = tid >> 2;         // 0..63 : A row within tile
    const int ac = (tid & 3) * 4;    // 0,4,8,12 : k within tile
    const int br = tid >> 4;         // 0..15 : B row (k) within tile
    const int bc = (tid & 15) * 4;   // col within tile

    for (int k0 = 0; k0 < K; k0 += BK) {
        // --- stage A tile (64 x 16), float4 per thread, transposed store ---
        float4 av;
        const int arow = m0 + ar;
        if (arow < M) {
            av = *(const float4*)(A + (size_t)arow * K + k0 + ac);
        } else {
            av = make_float4(0.f, 0.f, 0.f, 0.f);
        }
        As[ac + 0][ar] = av.x;
        As[ac + 1][ar] = av.y;
        As[ac + 2][ar] = av.z;
        As[ac + 3][ar] = av.w;

        // --- stage B tile (16 x 64), float4 per thread ---
        float4 bv = *(const float4*)(W + (size_t)(k0 + br) * N + n0 + bc);
        *(float4*)&Bs[br][bc] = bv;

        __syncthreads();

#pragma unroll
        for (int kk = 0; kk < BK; ++kk) {
            float4 a4 = *(const float4*)&As[kk][ty * 4];
            float4 b4 = *(const float4*)&Bs[kk][tx * 4];
            float a_[4] = {a4.x, a4.y, a4.z, a4.w};
            float b_[4] = {b4.x, b4.y, b4.z, b4.w};
#pragma unroll
            for (int i = 0; i < 4; ++i)
#pragma unroll
                for (int j = 0; j < 4; ++j) acc[i][j] = fmaf(a_[i], b_[j], acc[i][j]);
        }
        __syncthreads();
    }

    const int colbase = n0 + tx * 4;
    const float4 bb = *(const float4*)(bias + colbase);
#pragma unroll
    for (int i = 0; i < 4; ++i) {
        const int row = m0 + ty * 4 + i;
        if (row < M) {
            float4 o;
            o.x = acc[i][0] + bb.x;
            o.y = acc[i][1] + bb.y;
            o.z = acc[i][2] + bb.z;
            o.w = acc[i][3] + bb.w;
            *(float4*)(C + (size_t)row * N + colbase) = o;
        }
    }
}

// ---------------------------------------------------------------------------
// Fused softmax + sampling-location + bilinear sampling.
// One block per (b,q). 256 threads: phase 1 computes softmax weights and
// sampling coords into LDS; phase 2 thread = (h = tid>>5, d = tid&31) does
// 16 bilinear samples of the projected value and accumulates.
// vproj layout: (B, NUM_KEYS, HEADS*HEAD_DIM) row-major (plain GEMM output).
// out layout:   (B*Q, 256) with col = h*32+d.
// ---------------------------------------------------------------------------
__global__ __launch_bounds__(256)
void msda_sample_kernel(const float* __restrict__ off_all,
                        const float* __restrict__ attn_all,
                        const float* __restrict__ rp,
                        const float* __restrict__ vproj,
                        float* __restrict__ outbuf) {
    const int bq = blockIdx.x;          // 0..7199
    const int b = bq / QLEN;
    const int tid = threadIdx.x;

    __shared__ float s_attn[128];
    __shared__ float s_w[128];
    __shared__ float s_x[128];
    __shared__ float s_y[128];

    const float* offrow = off_all + (size_t)bq * 256;
    const float* attrow = attn_all + (size_t)bq * 128;

    if (tid < 128) s_attn[tid] = attrow[tid];
    __syncthreads();

    // per-head softmax over 16 (L*P) logits; 8 threads, serial 16-elem
    if (tid < 8) {
        const int h = tid;
        float m = -1e30f;
#pragma unroll
        for (int i = 0; i < 16; ++i) m = fmaxf(m, s_attn[h * 16 + i]);
        float e[16];
        float s = 0.f;
#pragma unroll
        for (int i = 0; i < 16; ++i) {
            e[i] = expf(s_attn[h * 16 + i] - m);
            s += e[i];
        }
        const float inv = 1.f / s;
#pragma unroll
        for (int i = 0; i < 16; ++i) s_w[h * 16 + i] = e[i] * inv;
    }

    // sampling coordinates: t encodes (h, l, p) = (t>>4, (t>>2)&3, t&3)
    if (tid < 128) {
        const int h = tid >> 4;
        const int l = (tid >> 2) & 3;
        const int p = tid & 3;
        const float offx = offrow[h * 32 + l * 8 + p * 2 + 0];
        const float offy = offrow[h * 32 + l * 8 + p * 2 + 1];
        const float Wl = (float)c_LW[l];
        const float Hl = (float)c_LH[l];
        const float rx = rp[((size_t)bq * 4 + l) * 2 + 0];
        const float ry = rp[((size_t)bq * 4 + l) * 2 + 1];
        const float lx = rx + offx / Wl;   // match reference op order
        const float ly = ry + offy / Hl;
        s_x[tid] = lx * Wl - 0.5f;
        s_y[tid] = ly * Hl - 0.5f;
    }
    __syncthreads();

    const int h = tid >> 5;
    const int d = tid & 31;
    const float* vb = vproj + (size_t)b * NUM_KEYS * 256 + h * 32 + d;

    float acc = 0.f;
#pragma unroll
    for (int l = 0; l < LEVELS; ++l) {
        const int Hl = c_LH[l];
        const int Wl = c_LW[l];
        const int s0 = c_LS[l];
#pragma unroll
        for (int p = 0; p < POINTS; ++p) {
            const int t2 = h * 16 + l * 4 + p;
            const float x = s_x[t2];
            const float y = s_y[t2];
            const float w = s_w[t2];
            const float x0f = floorf(x);
            const float y0f = floorf(y);
            const float wx = x - x0f;
            const float wy = y - y0f;
            const int x0 = (int)x0f;
            const int y0 = (int)y0f;
            const bool xin0 = (x0 >= 0) && (x0 < Wl);
            const bool xin1 = (x0 + 1 >= 0) && (x0 + 1 < Wl);
            const bool yin0 = (y0 >= 0) && (y0 < Hl);
            const bool yin1 = (y0 + 1 >= 0) && (y0 + 1 < Hl);
            float v00 = 0.f, v01 = 0.f, v10 = 0.f, v11 = 0.f;
            if (yin0) {
                const int rb = s0 + y0 * Wl;
                if (xin0) v00 = vb[(size_t)(rb + x0) * 256];
                if (xin1) v01 = vb[(size_t)(rb + x0 + 1) * 256];
            }
            if (yin1) {
                const int rb = s0 + (y0 + 1) * Wl;
                if (xin0) v10 = vb[(size_t)(rb + x0) * 256];
                if (xin1) v11 = vb[(size_t)(rb + x0 + 1) * 256];
            }
            const float samp = v00 * ((1.f - wx) * (1.f - wy)) +
                               v01 * (wx * (1.f - wy)) +
                               v10 * ((1.f - wx) * wy) +
                               v11 * (wx * wy);
            acc = fmaf(w, samp, acc);
        }
    }
    outbuf[(size_t)bq * 256 + tid] = acc;
}

// ---------------------------------------------------------------------------
extern "C" void kernel_launch(void* const* d_in, const int* in_sizes, int n_in,
                              void* d_out, int out_size, void* d_ws, size_t ws_size,
                              hipStream_t stream) {
    const float* query  = (const float*)d_in[0];
    const float* rp     = (const float*)d_in[1];
    const float* value  = (const float*)d_in[2];
    // d_in[3] spatial_shapes, d_in[4] level_start_index: compile-time constants
    const float* W_off  = (const float*)d_in[5];
    const float* b_off  = (const float*)d_in[6];
    const float* W_attn = (const float*)d_in[7];
    const float* b_attn = (const float*)d_in[8];
    const float* W_val  = (const float*)d_in[9];
    const float* b_val  = (const float*)d_in[10];
    const float* W_out  = (const float*)d_in[11];
    const float* b_out  = (const float*)d_in[12];
    float* out = (float*)d_out;

    float* ws      = (float*)d_ws;
    float* ws_v    = ws;                                   // 106352*256
    float* ws_off  = ws_v   + (size_t)MROWS_V * 256;       // 7200*256
    float* ws_attn = ws_off + (size_t)BQ * 256;            // 7200*128
    float* ws_msda = ws_attn + (size_t)BQ * 128;           // 7200*256

    // 1. value projection: (106352,256) @ (256,256) + b_val
    {
        dim3 grid((MROWS_V + BM - 1) / BM, 256 / BN);
        gemm_bias_kernel<<<grid, 256, 0, stream>>>(value, W_val, b_val, ws_v,
                                                   MROWS_V, 256, 256);
    }
    // 2. offset projection: (7200,256) @ (256,256) + b_off
    {
        dim3 grid((BQ + BM - 1) / BM, 256 / BN);
        gemm_bias_kernel<<<grid, 256, 0, stream>>>(query, W_off, b_off, ws_off,
                                                   BQ, 256, 256);
    }
    // 3. attention-logit projection: (7200,256) @ (256,128) + b_attn
    {
        dim3 grid((BQ + BM - 1) / BM, 128 / BN);
        gemm_bias_kernel<<<grid, 256, 0, stream>>>(query, W_attn, b_attn, ws_attn,
                                                   BQ, 128, 256);
    }
    // 4. softmax + locations + bilinear sampling
    msda_sample_kernel<<<BQ, 256, 0, stream>>>(ws_off, ws_attn, rp, ws_v, ws_msda);

    // 5. output projection: (7200,256) @ (256,256) + b_out -> d_out
    {
        dim3 grid((BQ + BM - 1) / BM, 256 / BN);
        gemm_bias_kernel<<<grid, 256, 0, stream>>>(ws_msda, W_out, b_out, out,
                                                   BQ, 256, 256);
    }
}

// Round 2
// 354.377 us; speedup vs baseline: 1.2589x; 1.2589x over previous
//
#include <hip/hip_runtime.h>
#include <hip/hip_bf16.h>
#include <math.h>

// Problem constants (fixed by setup_inputs)
#define BATCH 8
#define QLEN 900
#define EMBED 256
#define HEADS 8
#define LEVELS 4
#define POINTS 4
#define HEAD_DIM 32
#define NUM_KEYS 13294
#define BQ (BATCH * QLEN)          // 7200
#define MROWS_V (BATCH * NUM_KEYS) // 106352

__constant__ const int c_LH[4] = {100, 50, 25, 13};
__constant__ const int c_LW[4] = {100, 50, 25, 13};
__constant__ const int c_LS[4] = {0, 10000, 12500, 13125};

typedef __attribute__((ext_vector_type(8))) short bfrag;   // 8 bf16
typedef __attribute__((ext_vector_type(4))) float ffrag;   // 4 fp32 acc

// ---------------------------------------------------------------------------
// Cast W_val[K=256][N=256] fp32 -> WbT[N=256][K=256] bf16 (transposed).
// ---------------------------------------------------------------------------
__global__ __launch_bounds__(256)
void cast_wT_kernel(const float* __restrict__ W, unsigned short* __restrict__ WbT) {
    const int id = blockIdx.x * 256 + threadIdx.x;  // 65536 total
    const int n = id >> 8;
    const int k = id & 255;
    __hip_bfloat16 h = __float2bfloat16(W[k * 256 + n]);
    WbT[id] = *(unsigned short*)&h;
}

// ---------------------------------------------------------------------------
// Value projection: C[M,256] fp32 = bf16(A[M,256]) @ Wb[256,256] + bias
// BM=64, BN=256 (full N), BK=32. 256 threads = 4 waves; wave w owns rows
// [w*16, w*16+16) x all 256 cols = 16 MFMA tiles of 16x16.
// A cast to bf16 on the fly into LDS. WbT is pre-cast bf16 [N][K].
// ---------------------------------------------------------------------------
#define VB_M 64
#define VB_K 32
#define APAD 40   // row stride in bf16 elems (2-way bank alias only)

__global__ __launch_bounds__(256)
void vproj_mfma_kernel(const float* __restrict__ A,
                       const unsigned short* __restrict__ WbT,
                       const float* __restrict__ bias,
                       float* __restrict__ C, int M) {
    __shared__ unsigned short As[VB_M * APAD];    // 64 rows x 32k (pad 40)
    __shared__ unsigned short Bs[256 * APAD];     // 256 cols x 32k (pad 40)

    const int tid = threadIdx.x;
    const int wave = tid >> 6;
    const int lane = tid & 63;
    const int ln = lane & 15;
    const int quad = lane >> 4;
    const int koff = quad * 8;
    const int m0 = blockIdx.x * VB_M;

    ffrag acc[16];
#pragma unroll
    for (int j = 0; j < 16; ++j) acc[j] = (ffrag){0.f, 0.f, 0.f, 0.f};

    // A staging map: thread t -> row = t>>2, kc = (t&3)*8
    const int s_row = tid >> 2;
    const int s_kc = (tid & 3) * 8;
    const bool a_ok = (m0 + s_row) < M;
    const float* a_src = A + (size_t)(m0 + s_row) * 256 + s_kc;

    for (int k0 = 0; k0 < 256; k0 += VB_K) {
        // ---- stage A (64x32 fp32 -> bf16) ----
        float4 a0, a1;
        if (a_ok) {
            a0 = *(const float4*)(a_src + k0);
            a1 = *(const float4*)(a_src + k0 + 4);
        } else {
            a0 = make_float4(0.f, 0.f, 0.f, 0.f);
            a1 = a0;
        }
        {
            unsigned short* dst = &As[s_row * APAD + s_kc];
            float v[8] = {a0.x, a0.y, a0.z, a0.w, a1.x, a1.y, a1.z, a1.w};
            unsigned short u[8];
#pragma unroll
            for (int i = 0; i < 8; ++i) {
                __hip_bfloat16 h = __float2bfloat16(v[i]);
                u[i] = *(unsigned short*)&h;
            }
            *(uint4*)dst = *(uint4*)u;   // 16B store
        }
        // ---- stage B (WbT rows: 256 cols x 32 k bf16) ----
        {
            const unsigned short* src = WbT + tid * 256 + k0;
            unsigned short* dst = &Bs[tid * APAD];
#pragma unroll
            for (int i = 0; i < 4; ++i) {
                *(uint4*)(dst + i * 8) = *(const uint4*)(src + i * 8);
            }
        }
        __syncthreads();

        // ---- MFMA: wave's A-frag once, 16 col-tiles ----
        bfrag af = *(const bfrag*)&As[(wave * 16 + ln) * APAD + koff];
#pragma unroll
        for (int j = 0; j < 16; ++j) {
            bfrag bf = *(const bfrag*)&Bs[(j * 16 + ln) * APAD + koff];
            acc[j] = __builtin_amdgcn_mfma_f32_16x16x32_bf16(af, bf, acc[j], 0, 0, 0);
        }
        __syncthreads();
    }

    // epilogue: C[m0 + wave*16 + quad*4 + r][j*16 + ln]
#pragma unroll
    for (int j = 0; j < 16; ++j) {
        const int col = j * 16 + ln;
        const float bb = bias[col];
#pragma unroll
        for (int r = 0; r < 4; ++r) {
            const int row = m0 + wave * 16 + quad * 4 + r;
            if (row < M) C[(size_t)row * 256 + col] = acc[j][r] + bb;
        }
    }
}

// ---------------------------------------------------------------------------
// fp32 GEMM: C[M,N] = A[M,K] @ W[K,N] + bias[N]  (for the small projections)
// ---------------------------------------------------------------------------
#define BM 64
#define BN 64
#define BK 16

__global__ __launch_bounds__(256)
void gemm_bias_kernel(const float* __restrict__ A, const float* __restrict__ W,
                      const float* __restrict__ bias, float* __restrict__ C,
                      int M, int N, int K) {
    __shared__ float As[BK][BM + 4];
    __shared__ float Bs[BK][BN + 4];

    const int tid = threadIdx.x;
    const int tx = tid & 15;
    const int ty = tid >> 4;
    const int m0 = blockIdx.x * BM;
    const int n0 = blockIdx.y * BN;

    float acc[4][4];
#pragma unroll
    for (int i = 0; i < 4; ++i)
#pragma unroll
        for (int j = 0; j < 4; ++j) acc[i][j] = 0.f;

    const int ar = tid >> 2;
    const int ac = (tid & 3) * 4;
    const int br = tid >> 4;
    const int bc = (tid & 15) * 4;

    for (int k0 = 0; k0 < K; k0 += BK) {
        float4 av;
        const int arow = m0 + ar;
        if (arow < M) {
            av = *(const float4*)(A + (size_t)arow * K + k0 + ac);
        } else {
            av = make_float4(0.f, 0.f, 0.f, 0.f);
        }
        As[ac + 0][ar] = av.x;
        As[ac + 1][ar] = av.y;
        As[ac + 2][ar] = av.z;
        As[ac + 3][ar] = av.w;

        float4 bv = *(const float4*)(W + (size_t)(k0 + br) * N + n0 + bc);
        *(float4*)&Bs[br][bc] = bv;

        __syncthreads();

#pragma unroll
        for (int kk = 0; kk < BK; ++kk) {
            float4 a4 = *(const float4*)&As[kk][ty * 4];
            float4 b4 = *(const float4*)&Bs[kk][tx * 4];
            float a_[4] = {a4.x, a4.y, a4.z, a4.w};
            float b_[4] = {b4.x, b4.y, b4.z, b4.w};
#pragma unroll
            for (int i = 0; i < 4; ++i)
#pragma unroll
                for (int j = 0; j < 4; ++j) acc[i][j] = fmaf(a_[i], b_[j], acc[i][j]);
        }
        __syncthreads();
    }

    const int colbase = n0 + tx * 4;
    const float4 bb = *(const float4*)(bias + colbase);
#pragma unroll
    for (int i = 0; i < 4; ++i) {
        const int row = m0 + ty * 4 + i;
        if (row < M) {
            float4 o;
            o.x = acc[i][0] + bb.x;
            o.y = acc[i][1] + bb.y;
            o.z = acc[i][2] + bb.z;
            o.w = acc[i][3] + bb.w;
            *(float4*)(C + (size_t)row * N + colbase) = o;
        }
    }
}

// ---------------------------------------------------------------------------
// Fused softmax + sampling-location + bilinear sampling.
// Block = 256 threads = 2 queries. Thread = (q = tid>>7, h = (tid>>4)&7,
// dp = tid&15) handling dims 2dp, 2dp+1 via float2 gathers.
// ---------------------------------------------------------------------------
__global__ __launch_bounds__(256)
void msda_sample_kernel(const float* __restrict__ off_all,
                        const float* __restrict__ attn_all,
                        const float* __restrict__ rp,
                        const float* __restrict__ vproj,
                        float* __restrict__ outbuf) {
    const int bq0 = blockIdx.x * 2;
    const int tid = threadIdx.x;
    const int q = tid >> 7;        // 0/1
    const int t = tid & 127;

    __shared__ float s_attn[2][128];
    __shared__ float s_w[2][128];
    __shared__ float s_x[2][128];
    __shared__ float s_y[2][128];

    const int bq = bq0 + q;
    s_attn[q][t] = attn_all[(size_t)bq * 128 + t];
    __syncthreads();

    if (tid < 16) {
        const int qq = tid >> 3;
        const int h = tid & 7;
        float m = -1e30f;
#pragma unroll
        for (int i = 0; i < 16; ++i) m = fmaxf(m, s_attn[qq][h * 16 + i]);
        float e[16];
        float s = 0.f;
#pragma unroll
        for (int i = 0; i < 16; ++i) {
            e[i] = expf(s_attn[qq][h * 16 + i] - m);
            s += e[i];
        }
        const float inv = 1.f / s;
#pragma unroll
        for (int i = 0; i < 16; ++i) s_w[qq][h * 16 + i] = e[i] * inv;
    }

    // sampling coordinates: t encodes (h, l, p) = (t>>4, (t>>2)&3, t&3)
    {
        const int h = t >> 4;
        const int l = (t >> 2) & 3;
        const int p = t & 3;
        const float* offrow = off_all + (size_t)bq * 256;
        const float offx = offrow[h * 32 + l * 8 + p * 2 + 0];
        const float offy = offrow[h * 32 + l * 8 + p * 2 + 1];
        const float Wl = (float)c_LW[l];
        const float Hl = (float)c_LH[l];
        const float rx = rp[((size_t)bq * 4 + l) * 2 + 0];
        const float ry = rp[((size_t)bq * 4 + l) * 2 + 1];
        const float lx = rx + offx / Wl;
        const float ly = ry + offy / Hl;
        s_x[q][t] = lx * Wl - 0.5f;
        s_y[q][t] = ly * Hl - 0.5f;
    }
    __syncthreads();

    const int b = bq / QLEN;
    const int h = (tid >> 4) & 7;
    const int dp = tid & 15;
    const float* vb = vproj + (size_t)b * NUM_KEYS * 256 + h * 32 + dp * 2;

    float accx = 0.f, accy = 0.f;
#pragma unroll
    for (int l = 0; l < LEVELS; ++l) {
        const int Hl = c_LH[l];
        const int Wl = c_LW[l];
        const int s0 = c_LS[l];
#pragma unroll
        for (int p = 0; p < POINTS; ++p) {
            const int t2 = h * 16 + l * 4 + p;
            const float x = s_x[q][t2];
            const float y = s_y[q][t2];
            const float w = s_w[q][t2];
            const float x0f = floorf(x);
            const float y0f = floorf(y);
            const float wx = x - x0f;
            const float wy = y - y0f;
            const int x0 = (int)x0f;
            const int y0 = (int)y0f;
            const bool xin0 = (x0 >= 0) && (x0 < Wl);
            const bool xin1 = (x0 + 1 >= 0) && (x0 + 1 < Wl);
            const bool yin0 = (y0 >= 0) && (y0 < Hl);
            const bool yin1 = (y0 + 1 >= 0) && (y0 + 1 < Hl);
            float2 v00 = {0.f, 0.f}, v01 = {0.f, 0.f}, v10 = {0.f, 0.f}, v11 = {0.f, 0.f};
            if (yin0) {
                const int rb = s0 + y0 * Wl;
                if (xin0) v00 = *(const float2*)(vb + (size_t)(rb + x0) * 256);
                if (xin1) v01 = *(const float2*)(vb + (size_t)(rb + x0 + 1) * 256);
            }
            if (yin1) {
                const int rb = s0 + (y0 + 1) * Wl;
                if (xin0) v10 = *(const float2*)(vb + (size_t)(rb + x0) * 256);
                if (xin1) v11 = *(const float2*)(vb + (size_t)(rb + x0 + 1) * 256);
            }
            const float w00 = (1.f - wx) * (1.f - wy);
            const float w01 = wx * (1.f - wy);
            const float w10 = (1.f - wx) * wy;
            const float w11 = wx * wy;
            const float sx = v00.x * w00 + v01.x * w01 + v10.x * w10 + v11.x * w11;
            const float sy = v00.y * w00 + v01.y * w01 + v10.y * w10 + v11.y * w11;
            accx = fmaf(w, sx, accx);
            accy = fmaf(w, sy, accy);
        }
    }
    float2 o = {accx, accy};
    *(float2*)(outbuf + (size_t)bq * 256 + h * 32 + dp * 2) = o;
}

// ---------------------------------------------------------------------------
extern "C" void kernel_launch(void* const* d_in, const int* in_sizes, int n_in,
                              void* d_out, int out_size, void* d_ws, size_t ws_size,
                              hipStream_t stream) {
    const float* query  = (const float*)d_in[0];
    const float* rp     = (const float*)d_in[1];
    const float* value  = (const float*)d_in[2];
    const float* W_off  = (const float*)d_in[5];
    const float* b_off  = (const float*)d_in[6];
    const float* W_attn = (const float*)d_in[7];
    const float* b_attn = (const float*)d_in[8];
    const float* W_val  = (const float*)d_in[9];
    const float* b_val  = (const float*)d_in[10];
    const float* W_out  = (const float*)d_in[11];
    const float* b_out  = (const float*)d_in[12];
    float* out = (float*)d_out;

    float* ws      = (float*)d_ws;
    float* ws_v    = ws;                                   // 106352*256 f32
    float* ws_off  = ws_v   + (size_t)MROWS_V * 256;       // 7200*256 f32
    float* ws_attn = ws_off + (size_t)BQ * 256;            // 7200*128 f32
    float* ws_msda = ws_attn + (size_t)BQ * 128;           // 7200*256 f32
    unsigned short* ws_WbT = (unsigned short*)(ws_msda + (size_t)BQ * 256); // 256*256 bf16

    // 0. cast W_val -> bf16 transposed
    cast_wT_kernel<<<256, 256, 0, stream>>>(W_val, ws_WbT);

    // 1. value projection via bf16 MFMA
    {
        dim3 grid((MROWS_V + VB_M - 1) / VB_M);
        vproj_mfma_kernel<<<grid, 256, 0, stream>>>(value, ws_WbT, b_val, ws_v, MROWS_V);
    }
    // 2. offset projection (fp32)
    {
        dim3 grid((BQ + BM - 1) / BM, 256 / BN);
        gemm_bias_kernel<<<grid, 256, 0, stream>>>(query, W_off, b_off, ws_off,
                                                   BQ, 256, 256);
    }
    // 3. attention-logit projection (fp32)
    {
        dim3 grid((BQ + BM - 1) / BM, 128 / BN);
        gemm_bias_kernel<<<grid, 256, 0, stream>>>(query, W_attn, b_attn, ws_attn,
                                                   BQ, 128, 256);
    }
    // 4. softmax + locations + bilinear sampling (2 queries/block)
    msda_sample_kernel<<<BQ / 2, 256, 0, stream>>>(ws_off, ws_attn, rp, ws_v, ws_msda);

    // 5. output projection (fp32) -> d_out
    {
        dim3 grid((BQ + BM - 1) / BM, 256 / BN);
        gemm_bias_kernel<<<grid, 256, 0, stream>>>(ws_msda, W_out, b_out, out,
                                                   BQ, 256, 256);
    }
}

// Round 3
// 340.952 us; speedup vs baseline: 1.3084x; 1.0394x over previous
//
#include <hip/hip_runtime.h>
#include <hip/hip_bf16.h>
#include <math.h>
#include <type_traits>

// Problem constants (fixed by setup_inputs)
#define BATCH 8
#define QLEN 900
#define HEADS 8
#define LEVELS 4
#define POINTS 4
#define NUM_KEYS 13294
#define BQ (BATCH * QLEN)          // 7200
#define MROWS_V (BATCH * NUM_KEYS) // 106352

__constant__ const int c_LH[4] = {100, 50, 25, 13};
__constant__ const int c_LW[4] = {100, 50, 25, 13};
__constant__ const int c_LS[4] = {0, 10000, 12500, 13125};

typedef __attribute__((ext_vector_type(8))) short bfrag;   // 8 bf16
typedef __attribute__((ext_vector_type(4))) float ffrag;   // 4 fp32 acc

static __device__ __forceinline__ unsigned short f2bf(float f) {
    __hip_bfloat16 h = __float2bfloat16(f);
    return *(unsigned short*)&h;
}
static __device__ __forceinline__ float bf2f(unsigned int u16) {
    unsigned int v = u16 << 16;
    float f;
    __builtin_memcpy(&f, &v, 4);
    return f;
}

// ---------------------------------------------------------------------------
// Cast+transpose: WT[n][k] bf16 <- W[k][n] fp32.  K fixed at 256.
// grid = ncols blocks of 256 threads.
// ---------------------------------------------------------------------------
__global__ __launch_bounds__(256)
void cast_wT_kernel(const float* __restrict__ W, unsigned short* __restrict__ WT,
                    int ldw) {
    const int id = blockIdx.x * 256 + threadIdx.x;
    const int n = id >> 8;
    const int k = id & 255;
    WT[(size_t)n * 256 + k] = f2bf(W[(size_t)k * ldw + n]);
}

__global__ void concat_bias_kernel(const float* __restrict__ b0,
                                   const float* __restrict__ b1,
                                   float* __restrict__ dst) {
    const int t = threadIdx.x;  // 384
    dst[t] = (t < 256) ? b0[t] : b1[t - 256];
}

// ---------------------------------------------------------------------------
// bf16-MFMA GEMM: C[M,N] = bf16(A[M,256]) @ WT^T + bias.
// WT is [N][256] bf16 (pre-transposed). BM=64, BN=128, BK=64, 256 thr = 4 waves.
// Wave w: rows w*16..+16 x 128 cols = 8 MFMA tiles (acc[8] = 32 AGPRs).
// LDS row stride 72 shorts = 36 dwords == 4 mod 32 -> conflict-free b128 reads.
// ---------------------------------------------------------------------------
#define GST 72

template <typename AT, typename CT>
__global__ __launch_bounds__(256)
void gemm_mfma(const AT* __restrict__ A, const unsigned short* __restrict__ WT,
               const float* __restrict__ bias, CT* __restrict__ C,
               int M, int ldc) {
    __shared__ unsigned short As[64 * GST];
    __shared__ unsigned short Bs[128 * GST];
    const int tid = threadIdx.x;
    const int wave = tid >> 6;
    const int lane = tid & 63;
    const int ln = lane & 15;
    const int quad = lane >> 4;
    const int m0 = blockIdx.x * 64;
    const int n0 = blockIdx.y * 128;

    ffrag acc[8];
#pragma unroll
    for (int j = 0; j < 8; ++j) acc[j] = (ffrag){0.f, 0.f, 0.f, 0.f};

    const int ar = tid >> 2;            // A row in tile (0..63)
    const int akc = (tid & 3) * 16;     // A k-chunk (16 elems)
    const int brow = tid >> 1;          // B col in tile (0..127)
    const int bkc = (tid & 1) * 32;     // B k-chunk (32 elems)
    const bool a_ok = (m0 + ar) < M;
    const AT* a_src = A + (size_t)(m0 + ar) * 256 + akc;
    const unsigned short* b_src = WT + (size_t)(n0 + brow) * 256 + bkc;

    for (int k0 = 0; k0 < 256; k0 += 64) {
        // ---- stage A (64 x 64, -> bf16) ----
        unsigned short* adst = &As[ar * GST + akc];
        if constexpr (std::is_same<AT, float>::value) {
            float4 f0, f1, f2, f3;
            if (a_ok) {
                const float4* p = (const float4*)(a_src + k0);
                f0 = p[0]; f1 = p[1]; f2 = p[2]; f3 = p[3];
            } else {
                f0 = make_float4(0.f, 0.f, 0.f, 0.f);
                f1 = f0; f2 = f0; f3 = f0;
            }
            float v[16] = {f0.x, f0.y, f0.z, f0.w, f1.x, f1.y, f1.z, f1.w,
                           f2.x, f2.y, f2.z, f2.w, f3.x, f3.y, f3.z, f3.w};
            unsigned short u[16];
#pragma unroll
            for (int i = 0; i < 16; ++i) u[i] = f2bf(v[i]);
            ((uint4*)adst)[0] = ((uint4*)u)[0];
            ((uint4*)adst)[1] = ((uint4*)u)[1];
        } else {
            uint4 u0, u1;
            if (a_ok) {
                const uint4* p = (const uint4*)(a_src + k0);
                u0 = p[0]; u1 = p[1];
            } else {
                u0 = make_uint4(0, 0, 0, 0);
                u1 = u0;
            }
            ((uint4*)adst)[0] = u0;
            ((uint4*)adst)[1] = u1;
        }
        // ---- stage B (128 cols x 64 k) ----
        {
            const uint4* src = (const uint4*)(b_src + k0);
            uint4* dst = (uint4*)&Bs[brow * GST + bkc];
#pragma unroll
            for (int i = 0; i < 4; ++i) dst[i] = src[i];
        }
        __syncthreads();

#pragma unroll
        for (int ks = 0; ks < 2; ++ks) {
            const int koff = ks * 32 + quad * 8;
            bfrag af = *(const bfrag*)&As[(wave * 16 + ln) * GST + koff];
#pragma unroll
            for (int j = 0; j < 8; ++j) {
                bfrag bf = *(const bfrag*)&Bs[(j * 16 + ln) * GST + koff];
                acc[j] = __builtin_amdgcn_mfma_f32_16x16x32_bf16(af, bf, acc[j], 0, 0, 0);
            }
        }
        __syncthreads();
    }

    // epilogue: row = m0 + wave*16 + quad*4 + r, col = n0 + j*16 + ln
#pragma unroll
    for (int j = 0; j < 8; ++j) {
        const int col = n0 + j * 16 + ln;
        const float bb = bias[col];
#pragma unroll
        for (int r = 0; r < 4; ++r) {
            const int row = m0 + wave * 16 + quad * 4 + r;
            if (row < M) {
                const float v = acc[j][r] + bb;
                if constexpr (std::is_same<CT, unsigned short>::value) {
                    C[(size_t)row * ldc + col] = f2bf(v);
                } else {
                    C[(size_t)row * ldc + col] = v;
                }
            }
        }
    }
}

// ---------------------------------------------------------------------------
// Fused softmax + locations + bilinear sampling over bf16 values.
// Block = 256 threads = 8 queries. Phase 1: softmax + coords into LDS.
// Phase 2: thread = (q = tid>>5, h = (tid&31)>>2, dp = tid&3) owns 8 dims,
// gathers uint4 (8 bf16) per corner; 4 lanes cover a 64 B corner segment.
// ---------------------------------------------------------------------------
__global__ __launch_bounds__(256)
void msda_sample_kernel(const float* __restrict__ offattn,  // [BQ][384]
                        const float* __restrict__ rp,
                        const unsigned short* __restrict__ vb,  // (b,key,256) bf16
                        unsigned short* __restrict__ outb) {    // (bq,256) bf16
    const int bq0 = blockIdx.x * 8;
    const int tid = threadIdx.x;

    __shared__ float s_w[8][128];
    __shared__ float s_x[8][128];
    __shared__ float s_y[8][128];

    // load attn logits (8 x 128) into s_w
#pragma unroll
    for (int i = 0; i < 4; ++i) {
        const int e = i * 256 + tid;
        const int q = e >> 7, t = e & 127;
        s_w[q][t] = offattn[(size_t)(bq0 + q) * 384 + 256 + t];
    }
    __syncthreads();

    // softmax per (q,h): 64 threads
    if (tid < 64) {
        const int q = tid >> 3, h = tid & 7;
        float m = -1e30f;
#pragma unroll
        for (int i = 0; i < 16; ++i) m = fmaxf(m, s_w[q][h * 16 + i]);
        float e[16];
        float s = 0.f;
#pragma unroll
        for (int i = 0; i < 16; ++i) {
            e[i] = expf(s_w[q][h * 16 + i] - m);
            s += e[i];
        }
        const float inv = 1.f / s;
#pragma unroll
        for (int i = 0; i < 16; ++i) s_w[q][h * 16 + i] = e[i] * inv;
    }

    // sampling coordinates (8 x 128)
#pragma unroll
    for (int i = 0; i < 4; ++i) {
        const int e = i * 256 + tid;
        const int q = e >> 7, t = e & 127;
        const int h = t >> 4, l = (t >> 2) & 3, p = t & 3;
        const int bq = bq0 + q;
        const float2 off = *(const float2*)(offattn + (size_t)bq * 384 + h * 32 + l * 8 + p * 2);
        const float Wl = (float)c_LW[l];
        const float Hl = (float)c_LH[l];
        const float rx = rp[((size_t)bq * 4 + l) * 2 + 0];
        const float ry = rp[((size_t)bq * 4 + l) * 2 + 1];
        s_x[q][t] = (rx + off.x / Wl) * Wl - 0.5f;   // reference op order
        s_y[q][t] = (ry + off.y / Hl) * Hl - 0.5f;
    }
    __syncthreads();

    const int q = tid >> 5;
    const int s = tid & 31;
    const int h = s >> 2;
    const int dp = s & 3;
    const int bq = bq0 + q;
    const int b = bq / QLEN;
    const unsigned short* vbase = vb + (size_t)b * NUM_KEYS * 256 + h * 32 + dp * 8;

    float acc[8];
#pragma unroll
    for (int d = 0; d < 8; ++d) acc[d] = 0.f;

#pragma unroll
    for (int l = 0; l < LEVELS; ++l) {
        const int Hl = c_LH[l];
        const int Wl = c_LW[l];
        const int s0 = c_LS[l];
#pragma unroll
        for (int p = 0; p < POINTS; ++p) {
            const int t2 = h * 16 + l * 4 + p;
            const float x = s_x[q][t2];
            const float y = s_y[q][t2];
            const float w = s_w[q][t2];
            const float x0f = floorf(x);
            const float y0f = floorf(y);
            const float wx = x - x0f;
            const float wy = y - y0f;
            const int x0 = (int)x0f;
            const int y0 = (int)y0f;
            const float mx0 = ((unsigned)x0 < (unsigned)Wl) ? 1.f : 0.f;
            const float mx1 = ((unsigned)(x0 + 1) < (unsigned)Wl) ? 1.f : 0.f;
            const float my0 = ((unsigned)y0 < (unsigned)Hl) ? 1.f : 0.f;
            const float my1 = ((unsigned)(y0 + 1) < (unsigned)Hl) ? 1.f : 0.f;
            const int xc0 = min(max(x0, 0), Wl - 1);
            const int xc1 = min(max(x0 + 1, 0), Wl - 1);
            const int yc0 = min(max(y0, 0), Hl - 1);
            const int yc1 = min(max(y0 + 1, 0), Hl - 1);
            const float a00 = w * (1.f - wx) * (1.f - wy) * mx0 * my0;
            const float a01 = w * wx * (1.f - wy) * mx1 * my0;
            const float a10 = w * (1.f - wx) * wy * mx0 * my1;
            const float a11 = w * wx * wy * mx1 * my1;
            const size_t k00 = (size_t)(s0 + yc0 * Wl + xc0) * 256;
            const size_t k01 = (size_t)(s0 + yc0 * Wl + xc1) * 256;
            const size_t k10 = (size_t)(s0 + yc1 * Wl + xc0) * 256;
            const size_t k11 = (size_t)(s0 + yc1 * Wl + xc1) * 256;
            const uint4 r00 = *(const uint4*)(vbase + k00);
            const uint4 r01 = *(const uint4*)(vbase + k01);
            const uint4 r10 = *(const uint4*)(vbase + k10);
            const uint4 r11 = *(const uint4*)(vbase + k11);
            const unsigned int w00[4] = {r00.x, r00.y, r00.z, r00.w};
            const unsigned int w01[4] = {r01.x, r01.y, r01.z, r01.w};
            const unsigned int w10[4] = {r10.x, r10.y, r10.z, r10.w};
            const unsigned int w11[4] = {r11.x, r11.y, r11.z, r11.w};
#pragma unroll
            for (int i = 0; i < 4; ++i) {
                const float v00l = bf2f(w00[i] & 0xffffu), v00h = bf2f(w00[i] >> 16);
                const float v01l = bf2f(w01[i] & 0xffffu), v01h = bf2f(w01[i] >> 16);
                const float v10l = bf2f(w10[i] & 0xffffu), v10h = bf2f(w10[i] >> 16);
                const float v11l = bf2f(w11[i] & 0xffffu), v11h = bf2f(w11[i] >> 16);
                acc[i * 2 + 0] = fmaf(a00, v00l, fmaf(a01, v01l, fmaf(a10, v10l, fmaf(a11, v11l, acc[i * 2 + 0]))));
                acc[i * 2 + 1] = fmaf(a00, v00h, fmaf(a01, v01h, fmaf(a10, v10h, fmaf(a11, v11h, acc[i * 2 + 1]))));
            }
        }
    }

    unsigned short o[8];
#pragma unroll
    for (int d = 0; d < 8; ++d) o[d] = f2bf(acc[d]);
    *(uint4*)(outb + (size_t)bq * 256 + h * 32 + dp * 8) = *(uint4*)o;
}

// ---------------------------------------------------------------------------
extern "C" void kernel_launch(void* const* d_in, const int* in_sizes, int n_in,
                              void* d_out, int out_size, void* d_ws, size_t ws_size,
                              hipStream_t stream) {
    const float* query  = (const float*)d_in[0];
    const float* rp     = (const float*)d_in[1];
    const float* value  = (const float*)d_in[2];
    const float* W_off  = (const float*)d_in[5];
    const float* b_off  = (const float*)d_in[6];
    const float* W_attn = (const float*)d_in[7];
    const float* b_attn = (const float*)d_in[8];
    const float* W_val  = (const float*)d_in[9];
    const float* b_val  = (const float*)d_in[10];
    const float* W_out  = (const float*)d_in[11];
    const float* b_out  = (const float*)d_in[12];
    float* out = (float*)d_out;

    // workspace layout
    char* w = (char*)d_ws;
    unsigned short* ws_vb = (unsigned short*)w;                 // MROWS_V*256 bf16
    w += (size_t)MROWS_V * 256 * 2;
    float* ws_offattn = (float*)w;                              // BQ*384 f32
    w += (size_t)BQ * 384 * 4;
    unsigned short* ws_msda = (unsigned short*)w;               // BQ*256 bf16
    w += (size_t)BQ * 256 * 2;
    unsigned short* ws_Wv = (unsigned short*)w;  w += 256 * 256 * 2;   // [n][k]
    unsigned short* ws_Woa = (unsigned short*)w; w += 384 * 256 * 2;   // [n][k]
    unsigned short* ws_Wo = (unsigned short*)w;  w += 256 * 256 * 2;   // [n][k]
    float* ws_boa = (float*)w;                                   // 384 f32

    // 0. weight prep (bf16, transposed) + bias concat
    cast_wT_kernel<<<256, 256, 0, stream>>>(W_val, ws_Wv, 256);
    cast_wT_kernel<<<256, 256, 0, stream>>>(W_off, ws_Woa, 256);
    cast_wT_kernel<<<128, 256, 0, stream>>>(W_attn, ws_Woa + 256 * 256, 128);
    cast_wT_kernel<<<256, 256, 0, stream>>>(W_out, ws_Wo, 256);
    concat_bias_kernel<<<1, 384, 0, stream>>>(b_off, b_attn, ws_boa);

    // 1. value projection -> bf16 (M=106352, N=256)
    {
        dim3 grid((MROWS_V + 63) / 64, 2);
        gemm_mfma<float, unsigned short><<<grid, 256, 0, stream>>>(
            value, ws_Wv, b_val, ws_vb, MROWS_V, 256);
    }
    // 2. fused offset+attn projection -> fp32 (M=7200, N=384)
    {
        dim3 grid((BQ + 63) / 64, 3);
        gemm_mfma<float, float><<<grid, 256, 0, stream>>>(
            query, ws_Woa, ws_boa, ws_offattn, BQ, 384);
    }
    // 3. softmax + locations + bilinear sampling (8 queries/block)
    msda_sample_kernel<<<BQ / 8, 256, 0, stream>>>(ws_offattn, rp, ws_vb, ws_msda);

    // 4. output projection -> d_out fp32 (M=7200, N=256)
    {
        dim3 grid((BQ + 63) / 64, 2);
        gemm_mfma<unsigned short, float><<<grid, 256, 0, stream>>>(
            ws_msda, ws_Wo, b_out, out, BQ, 256);
    }
}

// Round 4
// 278.658 us; speedup vs baseline: 1.6010x; 1.2236x over previous
//
#include <hip/hip_runtime.h>
#include <hip/hip_bf16.h>
#include <math.h>
#include <type_traits>

// Problem constants (fixed by setup_inputs)
#define BATCH 8
#define QLEN 900
#define HEADS 8
#define LEVELS 4
#define POINTS 4
#define NUM_KEYS 13294
#define BQ (BATCH * QLEN)          // 7200
#define MROWS_V (BATCH * NUM_KEYS) // 106352

__constant__ const int c_LH[4] = {100, 50, 25, 13};
__constant__ const int c_LW[4] = {100, 50, 25, 13};
__constant__ const int c_LS[4] = {0, 10000, 12500, 13125};

typedef __attribute__((ext_vector_type(8))) short bfrag;   // 8 bf16
typedef __attribute__((ext_vector_type(4))) float ffrag;   // 4 fp32 acc

static __device__ __forceinline__ unsigned short f2bf(float f) {
    __hip_bfloat16 h = __float2bfloat16(f);
    return *(unsigned short*)&h;
}
static __device__ __forceinline__ float bf2f(unsigned int u16) {
    unsigned int v = u16 << 16;
    float f;
    __builtin_memcpy(&f, &v, 4);
    return f;
}

// ---------------------------------------------------------------------------
// Merged prep: cast+transpose all three weight matrices to bf16 [n][k],
// concat off/attn biases. One launch instead of five.
// ids: [0,64K) Wv | [64K,128K) Woa(off) | [128K,160K) Woa(attn)
//      [160K,224K) Wo | [224K,224K+384) bias concat
// ---------------------------------------------------------------------------
__global__ __launch_bounds__(256)
void prep_kernel(const float* __restrict__ W_val, const float* __restrict__ W_off,
                 const float* __restrict__ W_attn, const float* __restrict__ W_out,
                 const float* __restrict__ b_off, const float* __restrict__ b_attn,
                 unsigned short* __restrict__ Wv, unsigned short* __restrict__ Woa,
                 unsigned short* __restrict__ Wo, float* __restrict__ boa) {
    const int id = blockIdx.x * 256 + threadIdx.x;
    if (id < 65536) {
        const int n = id >> 8, k = id & 255;
        Wv[id] = f2bf(W_val[k * 256 + n]);
    } else if (id < 131072) {
        const int t = id - 65536;
        const int n = t >> 8, k = t & 255;
        Woa[t] = f2bf(W_off[k * 256 + n]);
    } else if (id < 163840) {
        const int t = id - 131072;
        const int n = t >> 8, k = t & 255;       // n in 0..127
        Woa[65536 + t] = f2bf(W_attn[k * 128 + n]);
    } else if (id < 229376) {
        const int t = id - 163840;
        const int n = t >> 8, k = t & 255;
        Wo[t] = f2bf(W_out[k * 256 + n]);
    } else if (id < 229760) {
        const int t = id - 229376;
        boa[t] = (t < 256) ? b_off[t] : b_attn[t - 256];
    }
}

// ---------------------------------------------------------------------------
// bf16-MFMA GEMM: C[M,N] = bf16(A[M,256]) @ WT^T + bias.
// WT is [N][256] bf16 (pre-transposed). BM=64, BN=128, BK=64, 256 thr = 4 waves.
// Wave w: rows w*16..+16 x 128 cols = 8 MFMA tiles (acc[8] = 32 AGPRs).
// LDS row stride 72 shorts = 36 dwords == 4 mod 32 -> conflict-free b128 reads.
// ---------------------------------------------------------------------------
#define GST 72

template <typename AT, typename CT>
__global__ __launch_bounds__(256)
void gemm_mfma(const AT* __restrict__ A, const unsigned short* __restrict__ WT,
               const float* __restrict__ bias, CT* __restrict__ C,
               int M, int ldc) {
    __shared__ unsigned short As[64 * GST];
    __shared__ unsigned short Bs[128 * GST];
    const int tid = threadIdx.x;
    const int wave = tid >> 6;
    const int lane = tid & 63;
    const int ln = lane & 15;
    const int quad = lane >> 4;
    const int m0 = blockIdx.x * 64;
    const int n0 = blockIdx.y * 128;

    ffrag acc[8];
#pragma unroll
    for (int j = 0; j < 8; ++j) acc[j] = (ffrag){0.f, 0.f, 0.f, 0.f};

    const int ar = tid >> 2;            // A row in tile (0..63)
    const int akc = (tid & 3) * 16;     // A k-chunk (16 elems)
    const int brow = tid >> 1;          // B col in tile (0..127)
    const int bkc = (tid & 1) * 32;     // B k-chunk (32 elems)
    const bool a_ok = (m0 + ar) < M;
    const AT* a_src = A + (size_t)(m0 + ar) * 256 + akc;
    const unsigned short* b_src = WT + (size_t)(n0 + brow) * 256 + bkc;

    for (int k0 = 0; k0 < 256; k0 += 64) {
        // ---- stage A (64 x 64, -> bf16) ----
        unsigned short* adst = &As[ar * GST + akc];
        if constexpr (std::is_same<AT, float>::value) {
            float4 f0, f1, f2, f3;
            if (a_ok) {
                const float4* p = (const float4*)(a_src + k0);
                f0 = p[0]; f1 = p[1]; f2 = p[2]; f3 = p[3];
            } else {
                f0 = make_float4(0.f, 0.f, 0.f, 0.f);
                f1 = f0; f2 = f0; f3 = f0;
            }
            float v[16] = {f0.x, f0.y, f0.z, f0.w, f1.x, f1.y, f1.z, f1.w,
                           f2.x, f2.y, f2.z, f2.w, f3.x, f3.y, f3.z, f3.w};
            unsigned short u[16];
#pragma unroll
            for (int i = 0; i < 16; ++i) u[i] = f2bf(v[i]);
            ((uint4*)adst)[0] = ((uint4*)u)[0];
            ((uint4*)adst)[1] = ((uint4*)u)[1];
        } else {
            uint4 u0, u1;
            if (a_ok) {
                const uint4* p = (const uint4*)(a_src + k0);
                u0 = p[0]; u1 = p[1];
            } else {
                u0 = make_uint4(0, 0, 0, 0);
                u1 = u0;
            }
            ((uint4*)adst)[0] = u0;
            ((uint4*)adst)[1] = u1;
        }
        // ---- stage B (128 cols x 64 k) ----
        {
            const uint4* src = (const uint4*)(b_src + k0);
            uint4* dst = (uint4*)&Bs[brow * GST + bkc];
#pragma unroll
            for (int i = 0; i < 4; ++i) dst[i] = src[i];
        }
        __syncthreads();

#pragma unroll
        for (int ks = 0; ks < 2; ++ks) {
            const int koff = ks * 32 + quad * 8;
            bfrag af = *(const bfrag*)&As[(wave * 16 + ln) * GST + koff];
#pragma unroll
            for (int j = 0; j < 8; ++j) {
                bfrag bf = *(const bfrag*)&Bs[(j * 16 + ln) * GST + koff];
                acc[j] = __builtin_amdgcn_mfma_f32_16x16x32_bf16(af, bf, acc[j], 0, 0, 0);
            }
        }
        __syncthreads();
    }

    // epilogue: row = m0 + wave*16 + quad*4 + r, col = n0 + j*16 + ln
#pragma unroll
    for (int j = 0; j < 8; ++j) {
        const int col = n0 + j * 16 + ln;
        const float bb = bias[col];
#pragma unroll
        for (int r = 0; r < 4; ++r) {
            const int row = m0 + wave * 16 + quad * 4 + r;
            if (row < M) {
                const float v = acc[j][r] + bb;
                if constexpr (std::is_same<CT, unsigned short>::value) {
                    C[(size_t)row * ldc + col] = f2bf(v);
                } else {
                    C[(size_t)row * ldc + col] = v;
                }
            }
        }
    }
}

// ---------------------------------------------------------------------------
// Fused softmax + locations + bilinear sampling over bf16 values.
// Block = 256 threads = 8 queries. Thread = (q = tid>>5, h, dp) owns 8 dims,
// gathers uint4 (8 bf16) per corner; 4 lanes cover a 64 B corner segment.
// __launch_bounds__(256,4): cap VGPR<=128 so 4 blocks/CU stay resident —
// round 3 measured VGPR=256 / occupancy 9.7% from full-unroll load hoisting.
// Level loop fully unrolled (compile-time H/W/start); point loop unroll 2
// limits in-flight gathers to 8 uint4.
// ---------------------------------------------------------------------------
__global__ __launch_bounds__(256, 4)
void msda_sample_kernel(const float* __restrict__ offattn,  // [BQ][384]
                        const float* __restrict__ rp,
                        const unsigned short* __restrict__ vb,  // (b,key,256) bf16
                        unsigned short* __restrict__ outb) {    // (bq,256) bf16
    const int bq0 = blockIdx.x * 8;
    const int tid = threadIdx.x;

    __shared__ float s_w[8][128];
    __shared__ float s_x[8][128];
    __shared__ float s_y[8][128];

    // load attn logits (8 x 128) into s_w
#pragma unroll
    for (int i = 0; i < 4; ++i) {
        const int e = i * 256 + tid;
        const int q = e >> 7, t = e & 127;
        s_w[q][t] = offattn[(size_t)(bq0 + q) * 384 + 256 + t];
    }
    __syncthreads();

    // softmax per (q,h): 64 threads
    if (tid < 64) {
        const int q = tid >> 3, h = tid & 7;
        float m = -1e30f;
#pragma unroll
        for (int i = 0; i < 16; ++i) m = fmaxf(m, s_w[q][h * 16 + i]);
        float e[16];
        float s = 0.f;
#pragma unroll
        for (int i = 0; i < 16; ++i) {
            e[i] = expf(s_w[q][h * 16 + i] - m);
            s += e[i];
        }
        const float inv = 1.f / s;
#pragma unroll
        for (int i = 0; i < 16; ++i) s_w[q][h * 16 + i] = e[i] * inv;
    }

    // sampling coordinates (8 x 128)
#pragma unroll
    for (int i = 0; i < 4; ++i) {
        const int e = i * 256 + tid;
        const int q = e >> 7, t = e & 127;
        const int h = t >> 4, l = (t >> 2) & 3, p = t & 3;
        const int bq = bq0 + q;
        const float2 off = *(const float2*)(offattn + (size_t)bq * 384 + h * 32 + l * 8 + p * 2);
        const float Wl = (float)c_LW[l];
        const float Hl = (float)c_LH[l];
        const float rx = rp[((size_t)bq * 4 + l) * 2 + 0];
        const float ry = rp[((size_t)bq * 4 + l) * 2 + 1];
        s_x[q][t] = (rx + off.x / Wl) * Wl - 0.5f;   // reference op order
        s_y[q][t] = (ry + off.y / Hl) * Hl - 0.5f;
    }
    __syncthreads();

    const int q = tid >> 5;
    const int s = tid & 31;
    const int h = s >> 2;
    const int dp = s & 3;
    const int bq = bq0 + q;
    const int b = bq / QLEN;
    const unsigned short* vbase = vb + (size_t)b * NUM_KEYS * 256 + h * 32 + dp * 8;

    float acc[8];
#pragma unroll
    for (int d = 0; d < 8; ++d) acc[d] = 0.f;

#pragma unroll
    for (int l = 0; l < LEVELS; ++l) {
        const int Hl = c_LH[l];
        const int Wl = c_LW[l];
        const int s0 = c_LS[l];
#pragma unroll 2
        for (int p = 0; p < POINTS; ++p) {
            const int t2 = h * 16 + l * 4 + p;
            const float x = s_x[q][t2];
            const float y = s_y[q][t2];
            const float w = s_w[q][t2];
            const float x0f = floorf(x);
            const float y0f = floorf(y);
            const float wx = x - x0f;
            const float wy = y - y0f;
            const int x0 = (int)x0f;
            const int y0 = (int)y0f;
            const float mx0 = ((unsigned)x0 < (unsigned)Wl) ? 1.f : 0.f;
            const float mx1 = ((unsigned)(x0 + 1) < (unsigned)Wl) ? 1.f : 0.f;
            const float my0 = ((unsigned)y0 < (unsigned)Hl) ? 1.f : 0.f;
            const float my1 = ((unsigned)(y0 + 1) < (unsigned)Hl) ? 1.f : 0.f;
            const int xc0 = min(max(x0, 0), Wl - 1);
            const int xc1 = min(max(x0 + 1, 0), Wl - 1);
            const int yc0 = min(max(y0, 0), Hl - 1);
            const int yc1 = min(max(y0 + 1, 0), Hl - 1);
            const float a00 = w * (1.f - wx) * (1.f - wy) * mx0 * my0;
            const float a01 = w * wx * (1.f - wy) * mx1 * my0;
            const float a10 = w * (1.f - wx) * wy * mx0 * my1;
            const float a11 = w * wx * wy * mx1 * my1;
            const size_t k00 = (size_t)(s0 + yc0 * Wl + xc0) * 256;
            const size_t k01 = (size_t)(s0 + yc0 * Wl + xc1) * 256;
            const size_t k10 = (size_t)(s0 + yc1 * Wl + xc0) * 256;
            const size_t k11 = (size_t)(s0 + yc1 * Wl + xc1) * 256;
            const uint4 r00 = *(const uint4*)(vbase + k00);
            const uint4 r01 = *(const uint4*)(vbase + k01);
            const uint4 r10 = *(const uint4*)(vbase + k10);
            const uint4 r11 = *(const uint4*)(vbase + k11);
            const unsigned int w00[4] = {r00.x, r00.y, r00.z, r00.w};
            const unsigned int w01[4] = {r01.x, r01.y, r01.z, r01.w};
            const unsigned int w10[4] = {r10.x, r10.y, r10.z, r10.w};
            const unsigned int w11[4] = {r11.x, r11.y, r11.z, r11.w};
#pragma unroll
            for (int i = 0; i < 4; ++i) {
                const float v00l = bf2f(w00[i] & 0xffffu), v00h = bf2f(w00[i] >> 16);
                const float v01l = bf2f(w01[i] & 0xffffu), v01h = bf2f(w01[i] >> 16);
                const float v10l = bf2f(w10[i] & 0xffffu), v10h = bf2f(w10[i] >> 16);
                const float v11l = bf2f(w11[i] & 0xffffu), v11h = bf2f(w11[i] >> 16);
                acc[i * 2 + 0] = fmaf(a00, v00l, fmaf(a01, v01l, fmaf(a10, v10l, fmaf(a11, v11l, acc[i * 2 + 0]))));
                acc[i * 2 + 1] = fmaf(a00, v00h, fmaf(a01, v01h, fmaf(a10, v10h, fmaf(a11, v11h, acc[i * 2 + 1]))));
            }
        }
    }

    unsigned short o[8];
#pragma unroll
    for (int d = 0; d < 8; ++d) o[d] = f2bf(acc[d]);
    *(uint4*)(outb + (size_t)bq * 256 + h * 32 + dp * 8) = *(uint4*)o;
}

// ---------------------------------------------------------------------------
extern "C" void kernel_launch(void* const* d_in, const int* in_sizes, int n_in,
                              void* d_out, int out_size, void* d_ws, size_t ws_size,
                              hipStream_t stream) {
    const float* query  = (const float*)d_in[0];
    const float* rp     = (const float*)d_in[1];
    const float* value  = (const float*)d_in[2];
    const float* W_off  = (const float*)d_in[5];
    const float* b_off  = (const float*)d_in[6];
    const float* W_attn = (const float*)d_in[7];
    const float* b_attn = (const float*)d_in[8];
    const float* W_val  = (const float*)d_in[9];
    const float* b_val  = (const float*)d_in[10];
    const float* W_out  = (const float*)d_in[11];
    const float* b_out  = (const float*)d_in[12];
    float* out = (float*)d_out;

    // workspace layout
    char* w = (char*)d_ws;
    unsigned short* ws_vb = (unsigned short*)w;                 // MROWS_V*256 bf16
    w += (size_t)MROWS_V * 256 * 2;
    float* ws_offattn = (float*)w;                              // BQ*384 f32
    w += (size_t)BQ * 384 * 4;
    unsigned short* ws_msda = (unsigned short*)w;               // BQ*256 bf16
    w += (size_t)BQ * 256 * 2;
    unsigned short* ws_Wv = (unsigned short*)w;  w += 256 * 256 * 2;   // [n][k]
    unsigned short* ws_Woa = (unsigned short*)w; w += 384 * 256 * 2;   // [n][k]
    unsigned short* ws_Wo = (unsigned short*)w;  w += 256 * 256 * 2;   // [n][k]
    float* ws_boa = (float*)w;                                   // 384 f32

    // 0. merged weight prep (bf16, transposed) + bias concat
    prep_kernel<<<898, 256, 0, stream>>>(W_val, W_off, W_attn, W_out,
                                         b_off, b_attn, ws_Wv, ws_Woa, ws_Wo, ws_boa);

    // 1. value projection -> bf16 (M=106352, N=256)
    {
        dim3 grid((MROWS_V + 63) / 64, 2);
        gemm_mfma<float, unsigned short><<<grid, 256, 0, stream>>>(
            value, ws_Wv, b_val, ws_vb, MROWS_V, 256);
    }
    // 2. fused offset+attn projection -> fp32 (M=7200, N=384)
    {
        dim3 grid((BQ + 63) / 64, 3);
        gemm_mfma<float, float><<<grid, 256, 0, stream>>>(
            query, ws_Woa, ws_boa, ws_offattn, BQ, 384);
    }
    // 3. softmax + locations + bilinear sampling (8 queries/block)
    msda_sample_kernel<<<BQ / 8, 256, 0, stream>>>(ws_offattn, rp, ws_vb, ws_msda);

    // 4. output projection -> d_out fp32 (M=7200, N=256)
    {
        dim3 grid((BQ + 63) / 64, 2);
        gemm_mfma<unsigned short, float><<<grid, 256, 0, stream>>>(
            ws_msda, ws_Wo, b_out, out, BQ, 256);
    }
}